// Round 1
// baseline (681.631 us; speedup 1.0000x reference)
//
#include <hip/hip_runtime.h>
#include <math.h>

#define N_ROWS 65536
#define K_CODES 1024
#define D_DIM 256

#define BM 128
#define BN 128
#define BD 16
#define TM 8
#define TN 8
#define TAU 0.02f

// ws layout (bytes)
#define WS_NFLAG   0        // unsigned
#define WS_CSQ     16       // float[1024]
#define WS_COUNTS  4112     // unsigned[1024]
#define WS_MINIDX  8208     // int[65536]
#define WS_LIST    270352   // int[65536]
#define WS_PART    532496   // double[16384]
#define NBLK_OUT   16384

__global__ void k_zero(unsigned* __restrict__ counts, unsigned* __restrict__ nflag) {
    int t = threadIdx.x;            // blockDim = 1024
    counts[t] = 0u;
    if (t == 0) *nflag = 0u;
}

__global__ void k_csq(const float* __restrict__ cb, float* __restrict__ csq) {
    int k = blockIdx.x * 256 + threadIdx.x;   // grid = 4
    const float4* c = (const float4*)(cb + (long)k * D_DIM);
    float s = 0.f;
#pragma unroll 8
    for (int i = 0; i < D_DIM / 4; i++) {
        float4 v = c[i];
        s += v.x * v.x + v.y * v.y + v.z * v.z + v.w * v.w;
    }
    csq[k] = s;
}

__device__ __forceinline__ void merge2(float& m1, int& i1, float& m2,
                                       float om1, int oi1, float om2) {
    float hi  = fmaxf(m1, om1);
    float lo2 = fminf(m2, om2);
    bool take = (om1 < m1) || (om1 == m1 && oi1 < i1);
    if (take) { m1 = om1; i1 = oi1; }
    m2 = fminf(hi, lo2);
}

__global__ __launch_bounds__(256, 2) void k_main(
    const float* __restrict__ x, const float* __restrict__ cb,
    const float* __restrict__ csq, int* __restrict__ min_idx,
    int* __restrict__ list, unsigned* __restrict__ nflag)
{
    __shared__ float Xs[BD][BM + 4];
    __shared__ float Cs[BD][BN + 4];

    const int tid = threadIdx.x;
    const int tx = tid & 15;        // code group
    const int ty = tid >> 4;        // row group
    const long n0 = (long)blockIdx.x * BM;

    float rm1[TM], rm2[TM];
    int   ri1[TM];
#pragma unroll
    for (int i = 0; i < TM; i++) { rm1[i] = INFINITY; rm2[i] = INFINITY; ri1[i] = 0; }

    for (int k0 = 0; k0 < K_CODES; k0 += BN) {
        float acc[TM][TN];
#pragma unroll
        for (int i = 0; i < TM; i++)
#pragma unroll
            for (int j = 0; j < TN; j++) acc[i][j] = 0.f;

        for (int d0 = 0; d0 < D_DIM; d0 += BD) {
            __syncthreads();
#pragma unroll
            for (int i = 0; i < 2; i++) {
                int idx4 = tid + i * 256;   // 0..511
                int row  = idx4 >> 2;       // 0..127
                int part = idx4 & 3;        // 0..3 (4 floats each)
                float4 xv = *(const float4*)(x + (n0 + row) * D_DIM + d0 + part * 4);
                Xs[part * 4 + 0][row] = xv.x; Xs[part * 4 + 1][row] = xv.y;
                Xs[part * 4 + 2][row] = xv.z; Xs[part * 4 + 3][row] = xv.w;
                float4 cv = *(const float4*)(cb + (long)(k0 + row) * D_DIM + d0 + part * 4);
                Cs[part * 4 + 0][row] = cv.x; Cs[part * 4 + 1][row] = cv.y;
                Cs[part * 4 + 2][row] = cv.z; Cs[part * 4 + 3][row] = cv.w;
            }
            __syncthreads();
#pragma unroll
            for (int dd = 0; dd < BD; dd++) {
                float4 xa = *(const float4*)&Xs[dd][ty * TM];
                float4 xb = *(const float4*)&Xs[dd][ty * TM + 4];
                float4 ca = *(const float4*)&Cs[dd][tx * TN];
                float4 cc = *(const float4*)&Cs[dd][tx * TN + 4];
                float xr[8] = {xa.x, xa.y, xa.z, xa.w, xb.x, xb.y, xb.z, xb.w};
                float cr[8] = {ca.x, ca.y, ca.z, ca.w, cc.x, cc.y, cc.z, cc.w};
#pragma unroll
                for (int i = 0; i < TM; i++)
#pragma unroll
                    for (int j = 0; j < TN; j++)
                        acc[i][j] = fmaf(xr[i], cr[j], acc[i][j]);
            }
        }

        // epilogue: distances + per-row (min1,min2,idx) across this k-tile
        float cs[TN];
#pragma unroll
        for (int j = 0; j < TN; j++) cs[j] = csq[k0 + tx * TN + j];

#pragma unroll
        for (int i = 0; i < TM; i++) {
            float m1 = INFINITY, m2 = INFINITY;
            int   i1 = 0;
#pragma unroll
            for (int j = 0; j < TN; j++) {
                float v = fmaf(-2.f, acc[i][j], cs[j]);   // ||c||^2 - 2 x.c (x_sq is row-constant)
                int   k = k0 + tx * TN + j;
                if (v < m1)      { m2 = m1; m1 = v; i1 = k; }
                else if (v < m2) { m2 = v; }
            }
            // butterfly across the 16 tx lanes (xor masks stay inside the group)
#pragma unroll
            for (int off = 1; off < 16; off <<= 1) {
                float om1 = __shfl_xor(m1, off, 64);
                float om2 = __shfl_xor(m2, off, 64);
                int   oi1 = __shfl_xor(i1, off, 64);
                merge2(m1, i1, m2, om1, oi1, om2);
            }
            merge2(rm1[i], ri1[i], rm2[i], m1, i1, m2);
        }
    }

    if (tx == 0) {
#pragma unroll
        for (int i = 0; i < TM; i++) {
            long n = n0 + (long)ty * TM + i;
            min_idx[n] = ri1[i];
            if (rm2[i] - rm1[i] < TAU) {    // near-tie: queue for fp64 re-rank
                unsigned p = atomicAdd(nflag, 1u);
                list[p] = (int)n;
            }
        }
    }
}

__global__ void k_refine(const float* __restrict__ x, const float* __restrict__ cb,
                         const unsigned* __restrict__ nflag, const int* __restrict__ list,
                         int* __restrict__ min_idx)
{
    __shared__ float  xs[D_DIM];
    __shared__ double bv[256];
    __shared__ int    bi[256];
    const int tid = threadIdx.x;
    const unsigned nf = *nflag;

    for (unsigned it = blockIdx.x; it < nf; it += gridDim.x) {
        const int row = list[it];
        __syncthreads();
        if (tid < 64) {
            float4 v = *(const float4*)(x + (long)row * D_DIM + tid * 4);
            *(float4*)&xs[tid * 4] = v;
        }
        __syncthreads();

        double best = 1e300;
        int    bidx = K_CODES;
        for (int kk = 0; kk < K_CODES / 256; kk++) {
            int k = kk * 256 + tid;
            const float* c = cb + (long)k * D_DIM;
            double s = 0.0;
            for (int d = 0; d < D_DIM; d += 4) {
                float4 cv = *(const float4*)(c + d);
                double d0 = (double)xs[d]     - (double)cv.x;
                double d1 = (double)xs[d + 1] - (double)cv.y;
                double d2 = (double)xs[d + 2] - (double)cv.z;
                double d3 = (double)xs[d + 3] - (double)cv.w;
                s += d0 * d0 + d1 * d1 + d2 * d2 + d3 * d3;
            }
            if (s < best || (s == best && k < bidx)) { best = s; bidx = k; }
        }
        bv[tid] = best; bi[tid] = bidx;
        __syncthreads();
        for (int off = 128; off > 0; off >>= 1) {
            if (tid < off) {
                double ov = bv[tid + off]; int oi = bi[tid + off];
                if (ov < bv[tid] || (ov == bv[tid] && oi < bi[tid])) { bv[tid] = ov; bi[tid] = oi; }
            }
            __syncthreads();
        }
        if (tid == 0) min_idx[row] = bi[0];
        __syncthreads();
    }
}

__global__ __launch_bounds__(256) void k_out(
    const float* __restrict__ x, const float* __restrict__ cb,
    const int* __restrict__ min_idx, float* __restrict__ out,
    unsigned* __restrict__ counts, double* __restrict__ partials)
{
    __shared__ double wsum[4];
    const int tid  = threadIdx.x;
    const int wave = tid >> 6;
    const int lane = tid & 63;
    const long n = (long)blockIdx.x * 4 + wave;
    const int idx = min_idx[n];

    float4 q  = *(const float4*)(cb + (long)idx * D_DIM + lane * 4);
    float4 xv = *(const float4*)(x + n * D_DIM + lane * 4);
    *(float4*)(out + n * D_DIM + lane * 4) = q;

    float d0 = xv.x - q.x, d1 = xv.y - q.y, d2 = xv.z - q.z, d3 = xv.w - q.w;
    double s = (double)d0 * d0 + (double)d1 * d1 + (double)d2 * d2 + (double)d3 * d3;
    for (int off = 32; off > 0; off >>= 1) s += __shfl_down(s, off, 64);

    if (lane == 0) {
        wsum[wave] = s;
        atomicAdd(&counts[idx], 1u);
        out[16777218L + n] = (float)idx;   // min_indices as float values
    }
    __syncthreads();
    if (tid == 0) partials[blockIdx.x] = wsum[0] + wsum[1] + wsum[2] + wsum[3];
}

__global__ void k_final(const double* __restrict__ partials,
                        const unsigned* __restrict__ counts, float* __restrict__ out)
{
    __shared__ double red[256];
    const int tid = threadIdx.x;

    double s = 0.0;
    for (int i = tid; i < NBLK_OUT; i += 256) s += partials[i];
    red[tid] = s;
    __syncthreads();
    for (int off = 128; off > 0; off >>= 1) { if (tid < off) red[tid] += red[tid + off]; __syncthreads(); }
    double loss = red[0] / (double)((long)N_ROWS * D_DIM);
    __syncthreads();

    double h = 0.0;
    for (int k = tid; k < K_CODES; k += 256) {
        double p = (double)counts[k] / (double)N_ROWS;
        h += p * log(p + 1e-10);
    }
    red[tid] = h;
    __syncthreads();
    for (int off = 128; off > 0; off >>= 1) { if (tid < off) red[tid] += red[tid + off]; __syncthreads(); }

    if (tid == 0) {
        out[16777216] = (float)loss;
        out[16777217] = (float)exp(-red[0]);
    }
}

extern "C" void kernel_launch(void* const* d_in, const int* in_sizes, int n_in,
                              void* d_out, int out_size, void* d_ws, size_t ws_size,
                              hipStream_t stream)
{
    const float* x  = (const float*)d_in[0];
    const float* cb = (const float*)d_in[1];
    float* out = (float*)d_out;
    char*  ws  = (char*)d_ws;

    unsigned* nflag    = (unsigned*)(ws + WS_NFLAG);
    float*    csq      = (float*)(ws + WS_CSQ);
    unsigned* counts   = (unsigned*)(ws + WS_COUNTS);
    int*      min_idx  = (int*)(ws + WS_MINIDX);
    int*      list     = (int*)(ws + WS_LIST);
    double*   partials = (double*)(ws + WS_PART);

    hipLaunchKernelGGL(k_zero,   dim3(1),            dim3(1024), 0, stream, counts, nflag);
    hipLaunchKernelGGL(k_csq,    dim3(K_CODES / 256), dim3(256), 0, stream, cb, csq);
    hipLaunchKernelGGL(k_main,   dim3(N_ROWS / BM),   dim3(256), 0, stream, x, cb, csq, min_idx, list, nflag);
    hipLaunchKernelGGL(k_refine, dim3(64),            dim3(256), 0, stream, x, cb, nflag, list, min_idx);
    hipLaunchKernelGGL(k_out,    dim3(N_ROWS / 4),    dim3(256), 0, stream, x, cb, min_idx, out, counts, partials);
    hipLaunchKernelGGL(k_final,  dim3(1),             dim3(256), 0, stream, partials, counts, out);
}

// Round 2
// 404.791 us; speedup vs baseline: 1.6839x; 1.6839x over previous
//
#include <hip/hip_runtime.h>
#include <math.h>

#define N_ROWS 65536
#define K_CODES 1024
#define D_DIM 256
#define TAU 0.4f

// ws layout (bytes) — small stuff only; f16 x lives in d_out's first 32 MB
#define WS_NFLAG   0        // unsigned
#define WS_CSQ     16       // float[1024]
#define WS_COUNTS  4112     // unsigned[1024]
#define WS_MINIDX  8208     // int[65536]
#define WS_LIST    270352   // int[65536]
#define WS_PART    532496   // double[16384]
#define WS_CBH     663568   // _Float16[1024*256]
#define NBLK_OUT   16384

typedef _Float16 f16x8 __attribute__((ext_vector_type(8)));
typedef float    f32x4 __attribute__((ext_vector_type(4)));

__device__ __forceinline__ void gl_lds16(const _Float16* g, _Float16* l) {
    __builtin_amdgcn_global_load_lds(
        (const __attribute__((address_space(1))) unsigned int*)g,
        (__attribute__((address_space(3))) unsigned int*)l, 16, 0, 0);
}

// ---- prep: fp32 -> f16 for x and cb, csq (fp32 from original), zero counts/nflag
__global__ __launch_bounds__(256) void k_prep(
    const float* __restrict__ x, const float* __restrict__ cb,
    _Float16* __restrict__ xh, _Float16* __restrict__ cbh,
    float* __restrict__ csq, unsigned* __restrict__ counts, unsigned* __restrict__ nflag)
{
    const int b = blockIdx.x;
    const int t = threadIdx.x;
    if (b < 8192) {
        // x conversion: 2048 f16 per block
        const long idx8 = (long)b * 2048 + t * 8;
        float4 v0 = *(const float4*)(x + idx8);
        float4 v1 = *(const float4*)(x + idx8 + 4);
        f16x8 h;
        h[0] = (_Float16)v0.x; h[1] = (_Float16)v0.y; h[2] = (_Float16)v0.z; h[3] = (_Float16)v0.w;
        h[4] = (_Float16)v1.x; h[5] = (_Float16)v1.y; h[6] = (_Float16)v1.z; h[7] = (_Float16)v1.w;
        *(f16x8*)(xh + idx8) = h;
    } else {
        // cb conversion + csq; 128 blocks cover 1024 rows (8 rows/block)
        const int b2 = b - 8192;
        const long idx8 = (long)b2 * 2048 + t * 8;
        float4 v0 = *(const float4*)(cb + idx8);
        float4 v1 = *(const float4*)(cb + idx8 + 4);
        f16x8 h;
        h[0] = (_Float16)v0.x; h[1] = (_Float16)v0.y; h[2] = (_Float16)v0.z; h[3] = (_Float16)v0.w;
        h[4] = (_Float16)v1.x; h[5] = (_Float16)v1.y; h[6] = (_Float16)v1.z; h[7] = (_Float16)v1.w;
        *(f16x8*)(cbh + idx8) = h;
        float sq = v0.x * v0.x + v0.y * v0.y + v0.z * v0.z + v0.w * v0.w
                 + v1.x * v1.x + v1.y * v1.y + v1.z * v1.z + v1.w * v1.w;
        for (int off = 16; off > 0; off >>= 1) sq += __shfl_down(sq, off, 32);
        if ((t & 31) == 0) csq[b2 * 8 + (t >> 5)] = sq;
        if (b2 < 4) counts[b2 * 256 + t] = 0u;
        if (b2 == 0 && t == 0) *nflag = 0u;
    }
}

__device__ __forceinline__ void merge2(float& m1, int& i1, float& m2,
                                       float om1, int oi1, float om2) {
    float hi  = fmaxf(m1, om1);
    float lo2 = fminf(m2, om2);
    bool take = (om1 < m1) || (om1 == m1 && oi1 < i1);
    if (take) { m1 = om1; i1 = oi1; }
    m2 = fminf(hi, lo2);
}

// ---- main: f16 MFMA distance GEMM + in-register top-2 argmin
__global__ __launch_bounds__(256) void k_main(
    const _Float16* __restrict__ xh, const _Float16* __restrict__ cbh,
    const float* __restrict__ csq, int* __restrict__ min_idx,
    int* __restrict__ list, unsigned* __restrict__ nflag)
{
    __shared__ __attribute__((aligned(16))) _Float16 As[128 * 32];
    __shared__ __attribute__((aligned(16))) _Float16 Bs[128 * 32];

    const int tid  = threadIdx.x;
    const int w    = tid >> 6;          // wave 0..3 -> rows w*32..w*32+31
    const int lane = tid & 63;
    const int rlow = lane & 15;
    const int quad = lane >> 4;
    const long n0  = (long)blockIdx.x * 128;

    // per-lane state: 8 rows (i in 0..1, v in 0..3), min over this lane's codes
    float sm1[8], sm2[8];
    int   si1[8];
#pragma unroll
    for (int s = 0; s < 8; s++) { sm1[s] = INFINITY; sm2[s] = INFINITY; si1[s] = 0; }

    for (int kt = 0; kt < 8; ++kt) {
        const int kbase = kt * 128;
        f32x4 acc[16];
        const f32x4 z = {0.f, 0.f, 0.f, 0.f};
#pragma unroll
        for (int t = 0; t < 16; t++) acc[t] = z;

        for (int d0 = 0; d0 < 256; d0 += 32) {
            __syncthreads();
#pragma unroll
            for (int r = 0; r < 2; ++r) {
                int o = r * 256 + tid;          // 0..511
                int grow = o >> 2;              // 0..127
                int part = o & 3;               // 8 f16 each
                gl_lds16(xh  + (n0 + grow) * 256 + d0 + part * 8, As + o * 8);
                gl_lds16(cbh + (long)(kbase + grow) * 256 + d0 + part * 8, Bs + o * 8);
            }
            __syncthreads();

            f16x8 a[2], b[8];
#pragma unroll
            for (int i = 0; i < 2; ++i)
                a[i] = *(const f16x8*)&As[(w * 32 + i * 16 + rlow) * 32 + quad * 8];
#pragma unroll
            for (int j = 0; j < 8; ++j)
                b[j] = *(const f16x8*)&Bs[(j * 16 + rlow) * 32 + quad * 8];
#pragma unroll
            for (int i = 0; i < 2; ++i)
#pragma unroll
                for (int j = 0; j < 8; ++j)
                    acc[i * 8 + j] = __builtin_amdgcn_mfma_f32_16x16x32_f16(
                        a[i], b[j], acc[i * 8 + j], 0, 0, 0);
        }

        // epilogue: fold this 128-code tile into per-lane top-2
#pragma unroll
        for (int j = 0; j < 8; ++j) {
            const int code = kbase + j * 16 + rlow;
            const float csj = csq[code];
#pragma unroll
            for (int i = 0; i < 2; ++i)
#pragma unroll
                for (int v = 0; v < 4; ++v) {
                    const int s = i * 4 + v;
                    float val = fmaf(-2.f, acc[i * 8 + j][v], csj);
                    bool lt = val < sm1[s];
                    sm2[s] = fminf(fmaxf(val, sm1[s]), sm2[s]);   // med3
                    si1[s] = lt ? code : si1[s];
                    sm1[s] = fminf(val, sm1[s]);
                }
        }
    }

    // cross-lane butterfly within the 16-lane col groups
#pragma unroll
    for (int s = 0; s < 8; ++s) {
#pragma unroll
        for (int m = 1; m < 16; m <<= 1) {
            float om1 = __shfl_xor(sm1[s], m, 64);
            float om2 = __shfl_xor(sm2[s], m, 64);
            int   oi1 = __shfl_xor(si1[s], m, 64);
            merge2(sm1[s], si1[s], sm2[s], om1, oi1, om2);
        }
    }

    if (rlow == 0) {
#pragma unroll
        for (int i = 0; i < 2; ++i)
#pragma unroll
            for (int v = 0; v < 4; ++v) {
                const int s = i * 4 + v;
                long n = n0 + w * 32 + i * 16 + quad * 4 + v;
                min_idx[n] = si1[s];
                if (sm2[s] - sm1[s] < TAU) {
                    unsigned p = atomicAdd(nflag, 1u);
                    list[p] = (int)n;
                }
            }
    }
}

// ---- exact fp64 full-scan re-rank for flagged (near-tie) rows, 2 rows/block-pass
__global__ __launch_bounds__(256) void k_refine(
    const float* __restrict__ x, const float* __restrict__ cb,
    const unsigned* __restrict__ nflag, const int* __restrict__ list,
    int* __restrict__ min_idx)
{
    __shared__ float  xs[2][D_DIM];
    __shared__ double bv[2][256];
    __shared__ int    bi[2][256];
    const int tid = threadIdx.x;
    const unsigned nf = *nflag;
    const unsigned npair = (nf + 1) >> 1;

    for (unsigned p = blockIdx.x; p < npair; p += gridDim.x) {
        const int r0 = list[2 * p];
        const bool has1 = (2 * p + 1 < nf);
        const int r1 = has1 ? list[2 * p + 1] : r0;
        __syncthreads();
        if (tid < 64)
            *(float4*)&xs[0][tid * 4] = *(const float4*)(x + (long)r0 * D_DIM + tid * 4);
        else if (tid < 128)
            *(float4*)&xs[1][(tid - 64) * 4] = *(const float4*)(x + (long)r1 * D_DIM + (tid - 64) * 4);
        __syncthreads();

        double b0 = 1e300, b1 = 1e300; int i0 = 0, i1 = 0;
        for (int kk = 0; kk < 4; ++kk) {
            int k = kk * 256 + tid;
            const float* c = cb + (long)k * D_DIM;
            double s0 = 0.0, s1 = 0.0;
            for (int d = 0; d < D_DIM; d += 4) {
                float4 cv = *(const float4*)(c + d);
                double e;
                e = (double)xs[0][d]     - (double)cv.x; s0 += e * e;
                e = (double)xs[0][d + 1] - (double)cv.y; s0 += e * e;
                e = (double)xs[0][d + 2] - (double)cv.z; s0 += e * e;
                e = (double)xs[0][d + 3] - (double)cv.w; s0 += e * e;
                e = (double)xs[1][d]     - (double)cv.x; s1 += e * e;
                e = (double)xs[1][d + 1] - (double)cv.y; s1 += e * e;
                e = (double)xs[1][d + 2] - (double)cv.z; s1 += e * e;
                e = (double)xs[1][d + 3] - (double)cv.w; s1 += e * e;
            }
            if (s0 < b0) { b0 = s0; i0 = k; }
            if (s1 < b1) { b1 = s1; i1 = k; }
        }
        bv[0][tid] = b0; bi[0][tid] = i0;
        bv[1][tid] = b1; bi[1][tid] = i1;
        __syncthreads();
        for (int off = 128; off > 0; off >>= 1) {
            if (tid < off) {
                if (bv[0][tid + off] < bv[0][tid] ||
                    (bv[0][tid + off] == bv[0][tid] && bi[0][tid + off] < bi[0][tid])) {
                    bv[0][tid] = bv[0][tid + off]; bi[0][tid] = bi[0][tid + off];
                }
                if (bv[1][tid + off] < bv[1][tid] ||
                    (bv[1][tid + off] == bv[1][tid] && bi[1][tid + off] < bi[1][tid])) {
                    bv[1][tid] = bv[1][tid + off]; bi[1][tid] = bi[1][tid + off];
                }
            }
            __syncthreads();
        }
        if (tid == 0) {
            min_idx[r0] = bi[0][0];
            if (has1) min_idx[r1] = bi[1][0];
        }
        __syncthreads();
    }
}

// ---- gather quantized rows, loss partials, histogram, index output
__global__ __launch_bounds__(256) void k_out(
    const float* __restrict__ x, const float* __restrict__ cb,
    const int* __restrict__ min_idx, float* __restrict__ out,
    unsigned* __restrict__ counts, double* __restrict__ partials)
{
    __shared__ double wsum[4];
    const int tid  = threadIdx.x;
    const int wave = tid >> 6;
    const int lane = tid & 63;
    const long n = (long)blockIdx.x * 4 + wave;
    const int idx = min_idx[n];

    float4 q  = *(const float4*)(cb + (long)idx * D_DIM + lane * 4);
    float4 xv = *(const float4*)(x + n * D_DIM + lane * 4);
    *(float4*)(out + n * D_DIM + lane * 4) = q;

    float d0 = xv.x - q.x, d1 = xv.y - q.y, d2 = xv.z - q.z, d3 = xv.w - q.w;
    double s = (double)d0 * d0 + (double)d1 * d1 + (double)d2 * d2 + (double)d3 * d3;
    for (int off = 32; off > 0; off >>= 1) s += __shfl_down(s, off, 64);

    if (lane == 0) {
        wsum[wave] = s;
        atomicAdd(&counts[idx], 1u);
        out[16777218L + n] = (float)idx;
    }
    __syncthreads();
    if (tid == 0) partials[blockIdx.x] = wsum[0] + wsum[1] + wsum[2] + wsum[3];
}

__global__ void k_final(const double* __restrict__ partials,
                        const unsigned* __restrict__ counts, float* __restrict__ out)
{
    __shared__ double red[256];
    const int tid = threadIdx.x;

    double s = 0.0;
    for (int i = tid; i < NBLK_OUT; i += 256) s += partials[i];
    red[tid] = s;
    __syncthreads();
    for (int off = 128; off > 0; off >>= 1) { if (tid < off) red[tid] += red[tid + off]; __syncthreads(); }
    double loss = red[0] / (double)((long)N_ROWS * D_DIM);
    __syncthreads();

    double h = 0.0;
    for (int k = tid; k < K_CODES; k += 256) {
        double p = (double)counts[k] / (double)N_ROWS;
        h += p * log(p + 1e-10);
    }
    red[tid] = h;
    __syncthreads();
    for (int off = 128; off > 0; off >>= 1) { if (tid < off) red[tid] += red[tid + off]; __syncthreads(); }

    if (tid == 0) {
        out[16777216] = (float)loss;
        out[16777217] = (float)exp(-red[0]);
    }
}

extern "C" void kernel_launch(void* const* d_in, const int* in_sizes, int n_in,
                              void* d_out, int out_size, void* d_ws, size_t ws_size,
                              hipStream_t stream)
{
    const float* x  = (const float*)d_in[0];
    const float* cb = (const float*)d_in[1];
    float* out = (float*)d_out;
    char*  ws  = (char*)d_ws;

    unsigned*  nflag    = (unsigned*)(ws + WS_NFLAG);
    float*     csq      = (float*)(ws + WS_CSQ);
    unsigned*  counts   = (unsigned*)(ws + WS_COUNTS);
    int*       min_idx  = (int*)(ws + WS_MINIDX);
    int*       list     = (int*)(ws + WS_LIST);
    double*    partials = (double*)(ws + WS_PART);
    _Float16*  cbh      = (_Float16*)(ws + WS_CBH);
    _Float16*  xh       = (_Float16*)d_out;   // scratch inside out; overwritten by k_out

    hipLaunchKernelGGL(k_prep,   dim3(8192 + 128), dim3(256), 0, stream, x, cb, xh, cbh, csq, counts, nflag);
    hipLaunchKernelGGL(k_main,   dim3(N_ROWS / 128), dim3(256), 0, stream, xh, cbh, csq, min_idx, list, nflag);
    hipLaunchKernelGGL(k_refine, dim3(1024), dim3(256), 0, stream, x, cb, nflag, list, min_idx);
    hipLaunchKernelGGL(k_out,    dim3(N_ROWS / 4), dim3(256), 0, stream, x, cb, min_idx, out, counts, partials);
    hipLaunchKernelGGL(k_final,  dim3(1), dim3(256), 0, stream, partials, counts, out);
}

// Round 3
// 387.435 us; speedup vs baseline: 1.7593x; 1.0448x over previous
//
#include <hip/hip_runtime.h>
#include <math.h>

#define N_ROWS 65536
#define K_CODES 1024
#define D_DIM 256
#define TAU 0.15f

// ws layout (bytes)
#define WS_NFLAG   0        // unsigned
#define WS_CSQ     16       // float[1024]
#define WS_COUNTS  4112     // unsigned[1024]
#define WS_MINIDX  8208     // int[65536]
#define WS_LIST    270352   // int[65536]
#define WS_PART    532496   // double[256]
#define WS_CBH     534544   // _Float16[1024*256]  (16B aligned)
// f16 x (32 MB) lives in d_out floats [0, 8388608); xsq in d_out floats
// [16777218, 16777218+65536) — both regions are read before k_out overwrites.

typedef _Float16 f16x8 __attribute__((ext_vector_type(8)));
typedef float    f32x4 __attribute__((ext_vector_type(4)));

__device__ __forceinline__ void gl_lds16(const _Float16* g, _Float16* l) {
    __builtin_amdgcn_global_load_lds(
        (const __attribute__((address_space(1))) unsigned int*)g,
        (__attribute__((address_space(3))) unsigned int*)l, 16, 0, 0);
}

// ---- prep: fp32 -> f16 for x and cb; xsq per row; csq per code; zero counts/nflag
__global__ __launch_bounds__(256) void k_prep(
    const float* __restrict__ x, const float* __restrict__ cb,
    _Float16* __restrict__ xh, _Float16* __restrict__ cbh,
    float* __restrict__ xsq, float* __restrict__ csq,
    unsigned* __restrict__ counts, unsigned* __restrict__ nflag)
{
    const int b = blockIdx.x;
    const int t = threadIdx.x;
    if (b < 8192) {
        const long idx8 = (long)b * 2048 + t * 8;
        float4 v0 = *(const float4*)(x + idx8);
        float4 v1 = *(const float4*)(x + idx8 + 4);
        f16x8 h;
        h[0] = (_Float16)v0.x; h[1] = (_Float16)v0.y; h[2] = (_Float16)v0.z; h[3] = (_Float16)v0.w;
        h[4] = (_Float16)v1.x; h[5] = (_Float16)v1.y; h[6] = (_Float16)v1.z; h[7] = (_Float16)v1.w;
        *(f16x8*)(xh + idx8) = h;
        float sq = v0.x * v0.x + v0.y * v0.y + v0.z * v0.z + v0.w * v0.w
                 + v1.x * v1.x + v1.y * v1.y + v1.z * v1.z + v1.w * v1.w;
        for (int off = 16; off > 0; off >>= 1) sq += __shfl_down(sq, off, 32);
        if ((t & 31) == 0) xsq[b * 8 + (t >> 5)] = sq;
    } else {
        const int b2 = b - 8192;
        const long idx8 = (long)b2 * 2048 + t * 8;
        float4 v0 = *(const float4*)(cb + idx8);
        float4 v1 = *(const float4*)(cb + idx8 + 4);
        f16x8 h;
        h[0] = (_Float16)v0.x; h[1] = (_Float16)v0.y; h[2] = (_Float16)v0.z; h[3] = (_Float16)v0.w;
        h[4] = (_Float16)v1.x; h[5] = (_Float16)v1.y; h[6] = (_Float16)v1.z; h[7] = (_Float16)v1.w;
        *(f16x8*)(cbh + idx8) = h;
        float sq = v0.x * v0.x + v0.y * v0.y + v0.z * v0.z + v0.w * v0.w
                 + v1.x * v1.x + v1.y * v1.y + v1.z * v1.z + v1.w * v1.w;
        for (int off = 16; off > 0; off >>= 1) sq += __shfl_down(sq, off, 32);
        if ((t & 31) == 0) csq[b2 * 8 + (t >> 5)] = sq;
        if (b2 < 4) counts[b2 * 256 + t] = 0u;
        if (b2 == 0 && t == 0) *nflag = 0u;
    }
}

__device__ __forceinline__ void merge2(float& m1, int& i1, float& m2,
                                       float om1, int oi1, float om2) {
    float hi  = fmaxf(m1, om1);
    float lo2 = fminf(m2, om2);
    bool take = (om1 < m1) || (om1 == m1 && oi1 < i1);
    if (take) { m1 = om1; i1 = oi1; }
    m2 = fminf(hi, lo2);
}

// ---- main: 256-row x 128-code MFMA tiles, top-2 argmin, loss partials
__global__ __launch_bounds__(256, 2) void k_main(
    const _Float16* __restrict__ xh, const _Float16* __restrict__ cbh,
    const float* __restrict__ csq, const float* __restrict__ xsq,
    int* __restrict__ min_idx, int* __restrict__ list,
    unsigned* __restrict__ nflag, double* __restrict__ partials)
{
    __shared__ __attribute__((aligned(16))) _Float16 As[256 * 32]; // 16 KB
    __shared__ __attribute__((aligned(16))) _Float16 Bs[128 * 32]; // 8 KB
    __shared__ double red[16];

    const int tid  = threadIdx.x;
    const int w    = tid >> 6;          // wave -> rows w*64 .. w*64+63
    const int lane = tid & 63;
    const int rlow = lane & 15;
    const int quad = lane >> 4;
    const long n0  = (long)blockIdx.x * 256;

    float sm1[16], sm2[16];
    int   si1[16];
#pragma unroll
    for (int s = 0; s < 16; s++) { sm1[s] = INFINITY; sm2[s] = INFINITY; si1[s] = 0; }

    for (int kt = 0; kt < 8; ++kt) {
        const int kbase = kt * 128;
        f32x4 acc[32];
        const f32x4 z = {0.f, 0.f, 0.f, 0.f};
#pragma unroll
        for (int t = 0; t < 32; t++) acc[t] = z;

        for (int d0 = 0; d0 < 256; d0 += 32) {
            __syncthreads();
#pragma unroll
            for (int r = 0; r < 4; ++r) {
                int o = r * 256 + tid;
                gl_lds16(xh + (n0 + (o >> 2)) * 256 + d0 + (o & 3) * 8, As + o * 8);
            }
#pragma unroll
            for (int r = 0; r < 2; ++r) {
                int o = r * 256 + tid;
                gl_lds16(cbh + (long)(kbase + (o >> 2)) * 256 + d0 + (o & 3) * 8, Bs + o * 8);
            }
            __syncthreads();

            f16x8 a[4], b[8];
#pragma unroll
            for (int i = 0; i < 4; ++i)
                a[i] = *(const f16x8*)&As[(w * 64 + i * 16 + rlow) * 32 + quad * 8];
#pragma unroll
            for (int j = 0; j < 8; ++j)
                b[j] = *(const f16x8*)&Bs[(j * 16 + rlow) * 32 + quad * 8];
#pragma unroll
            for (int i = 0; i < 4; ++i)
#pragma unroll
                for (int j = 0; j < 8; ++j)
                    acc[i * 8 + j] = __builtin_amdgcn_mfma_f32_16x16x32_f16(
                        a[i], b[j], acc[i * 8 + j], 0, 0, 0);
        }

#pragma unroll
        for (int j = 0; j < 8; ++j) {
            const int code = kbase + j * 16 + rlow;
            const float csj = csq[code];
#pragma unroll
            for (int i = 0; i < 4; ++i)
#pragma unroll
                for (int v = 0; v < 4; ++v) {
                    const int s = i * 4 + v;
                    float val = fmaf(-2.f, acc[i * 8 + j][v], csj);
                    bool lt = val < sm1[s];
                    sm2[s] = fminf(fmaxf(val, sm1[s]), sm2[s]);
                    si1[s] = lt ? code : si1[s];
                    sm1[s] = fminf(val, sm1[s]);
                }
        }
    }

#pragma unroll
    for (int s = 0; s < 16; ++s) {
#pragma unroll
        for (int m = 1; m < 16; m <<= 1) {
            float om1 = __shfl_xor(sm1[s], m, 64);
            float om2 = __shfl_xor(sm2[s], m, 64);
            int   oi1 = __shfl_xor(si1[s], m, 64);
            merge2(sm1[s], si1[s], sm2[s], om1, oi1, om2);
        }
    }

    double lsum = 0.0;
    if (rlow == 0) {
#pragma unroll
        for (int i = 0; i < 4; ++i)
#pragma unroll
            for (int v = 0; v < 4; ++v) {
                const int s = i * 4 + v;
                long n = n0 + w * 64 + i * 16 + quad * 4 + v;
                min_idx[n] = si1[s];
                lsum += (double)xsq[n] + (double)sm1[s];
                if (sm2[s] - sm1[s] < TAU) {
                    unsigned p = atomicAdd(nflag, 1u);
                    list[p] = (int)n;
                }
            }
    }
    __syncthreads();
    if (rlow == 0) red[w * 4 + quad] = lsum;
    __syncthreads();
    if (tid == 0) {
        double t = 0.0;
#pragma unroll
        for (int i = 0; i < 16; ++i) t += red[i];
        partials[blockIdx.x] = t;
    }
}

// ---- exact fp64 full-scan re-rank for flagged rows, 2 rows/pass, 4 acc chains/row
__global__ __launch_bounds__(256) void k_refine(
    const float* __restrict__ x, const float* __restrict__ cb,
    const unsigned* __restrict__ nflag, const int* __restrict__ list,
    int* __restrict__ min_idx)
{
    __shared__ float  xs[2][D_DIM];
    __shared__ double bv[2][256];
    __shared__ int    bi[2][256];
    const int tid = threadIdx.x;
    const unsigned nf = *nflag;
    const unsigned npair = (nf + 1) >> 1;

    for (unsigned p = blockIdx.x; p < npair; p += gridDim.x) {
        const int r0 = list[2 * p];
        const bool has1 = (2 * p + 1 < nf);
        const int r1 = has1 ? list[2 * p + 1] : r0;
        __syncthreads();
        if (tid < 64)
            *(float4*)&xs[0][tid * 4] = *(const float4*)(x + (long)r0 * D_DIM + tid * 4);
        else if (tid < 128)
            *(float4*)&xs[1][(tid - 64) * 4] = *(const float4*)(x + (long)r1 * D_DIM + (tid - 64) * 4);
        __syncthreads();

        double b0 = 1e300, b1 = 1e300; int i0 = 0, i1 = 0;
        for (int kk = 0; kk < 4; ++kk) {
            int k = kk * 256 + tid;
            const float* c = cb + (long)k * D_DIM;
            double s0a = 0.0, s0b = 0.0, s0c = 0.0, s0d = 0.0;
            double s1a = 0.0, s1b = 0.0, s1c = 0.0, s1d = 0.0;
            for (int d = 0; d < D_DIM; d += 4) {
                float4 cv = *(const float4*)(c + d);
                double e;
                e = (double)xs[0][d]     - (double)cv.x; s0a += e * e;
                e = (double)xs[0][d + 1] - (double)cv.y; s0b += e * e;
                e = (double)xs[0][d + 2] - (double)cv.z; s0c += e * e;
                e = (double)xs[0][d + 3] - (double)cv.w; s0d += e * e;
                e = (double)xs[1][d]     - (double)cv.x; s1a += e * e;
                e = (double)xs[1][d + 1] - (double)cv.y; s1b += e * e;
                e = (double)xs[1][d + 2] - (double)cv.z; s1c += e * e;
                e = (double)xs[1][d + 3] - (double)cv.w; s1d += e * e;
            }
            double s0 = (s0a + s0b) + (s0c + s0d);
            double s1 = (s1a + s1b) + (s1c + s1d);
            if (s0 < b0) { b0 = s0; i0 = k; }
            if (s1 < b1) { b1 = s1; i1 = k; }
        }
        bv[0][tid] = b0; bi[0][tid] = i0;
        bv[1][tid] = b1; bi[1][tid] = i1;
        __syncthreads();
        for (int off = 128; off > 0; off >>= 1) {
            if (tid < off) {
                if (bv[0][tid + off] < bv[0][tid] ||
                    (bv[0][tid + off] == bv[0][tid] && bi[0][tid + off] < bi[0][tid])) {
                    bv[0][tid] = bv[0][tid + off]; bi[0][tid] = bi[0][tid + off];
                }
                if (bv[1][tid + off] < bv[1][tid] ||
                    (bv[1][tid + off] == bv[1][tid] && bi[1][tid + off] < bi[1][tid])) {
                    bv[1][tid] = bv[1][tid + off]; bi[1][tid] = bi[1][tid + off];
                }
            }
            __syncthreads();
        }
        if (tid == 0) {
            min_idx[r0] = bi[0][0];
            if (has1) min_idx[r1] = bi[1][0];
        }
        __syncthreads();
    }
}

// ---- gather quantized rows, histogram, index output (no x re-read, no loss here)
__global__ __launch_bounds__(256) void k_out(
    const float* __restrict__ cb, const int* __restrict__ min_idx,
    float* __restrict__ out, unsigned* __restrict__ counts)
{
    const int tid  = threadIdx.x;
    const int wave = tid >> 6;
    const int lane = tid & 63;
    const long n = (long)blockIdx.x * 4 + wave;
    const int idx = min_idx[n];

    float4 q = *(const float4*)(cb + (long)idx * D_DIM + lane * 4);
    *(float4*)(out + n * D_DIM + lane * 4) = q;

    if (lane == 0) {
        atomicAdd(&counts[idx], 1u);
        out[16777218L + n] = (float)idx;
    }
}

__global__ void k_final(const double* __restrict__ partials,
                        const unsigned* __restrict__ counts, float* __restrict__ out)
{
    __shared__ double red[256];
    const int tid = threadIdx.x;

    red[tid] = partials[tid];
    __syncthreads();
    for (int off = 128; off > 0; off >>= 1) { if (tid < off) red[tid] += red[tid + off]; __syncthreads(); }
    double loss = red[0] / (double)((long)N_ROWS * D_DIM);
    __syncthreads();

    double h = 0.0;
    for (int k = tid; k < K_CODES; k += 256) {
        double p = (double)counts[k] / (double)N_ROWS;
        h += p * log(p + 1e-10);
    }
    red[tid] = h;
    __syncthreads();
    for (int off = 128; off > 0; off >>= 1) { if (tid < off) red[tid] += red[tid + off]; __syncthreads(); }

    if (tid == 0) {
        out[16777216] = (float)loss;
        out[16777217] = (float)exp(-red[0]);
    }
}

extern "C" void kernel_launch(void* const* d_in, const int* in_sizes, int n_in,
                              void* d_out, int out_size, void* d_ws, size_t ws_size,
                              hipStream_t stream)
{
    const float* x  = (const float*)d_in[0];
    const float* cb = (const float*)d_in[1];
    float* out = (float*)d_out;
    char*  ws  = (char*)d_ws;

    unsigned*  nflag    = (unsigned*)(ws + WS_NFLAG);
    float*     csq      = (float*)(ws + WS_CSQ);
    unsigned*  counts   = (unsigned*)(ws + WS_COUNTS);
    int*       min_idx  = (int*)(ws + WS_MINIDX);
    int*       list     = (int*)(ws + WS_LIST);
    double*    partials = (double*)(ws + WS_PART);
    _Float16*  cbh      = (_Float16*)(ws + WS_CBH);
    _Float16*  xh       = (_Float16*)d_out;          // scratch in out; overwritten by k_out
    float*     xsq      = out + 16777218L;           // scratch in index region; overwritten by k_out

    hipLaunchKernelGGL(k_prep,   dim3(8192 + 128), dim3(256), 0, stream,
                       x, cb, xh, cbh, xsq, csq, counts, nflag);
    hipLaunchKernelGGL(k_main,   dim3(N_ROWS / 256), dim3(256), 0, stream,
                       xh, cbh, csq, xsq, min_idx, list, nflag, partials);
    hipLaunchKernelGGL(k_refine, dim3(1024), dim3(256), 0, stream, x, cb, nflag, list, min_idx);
    hipLaunchKernelGGL(k_out,    dim3(N_ROWS / 4), dim3(256), 0, stream, cb, min_idx, out, counts);
    hipLaunchKernelGGL(k_final,  dim3(1), dim3(256), 0, stream, partials, counts, out);
}

// Round 4
// 360.173 us; speedup vs baseline: 1.8925x; 1.0757x over previous
//
#include <hip/hip_runtime.h>
#include <math.h>

#define N_ROWS 65536
#define K_CODES 1024
#define D_DIM 256
#define TAU 0.12f

// ws layout (bytes)
#define WS_NFLAG   0        // unsigned
#define WS_CSQ     16       // float[1024]
#define WS_COUNTS  4112     // unsigned[1024]
#define WS_MINIDX  8208     // int[65536]
#define WS_LIST    270352   // int[65536]
#define WS_PART    532496   // double[256]
#define WS_CSQD    534544   // double[1024]
#define WS_CBH     542736   // _Float16[1024*256] (16B aligned)
// d_out scratch (floats):
//   xh  (f16 x, 32MB)   : [0, 8388608)
//   m1h float[2][65536] : [8388608, 8519680)
//   m2h float[2][65536] : [8519680, 8650752)
//   i1f float[2][65536] : [8650752, 8781824)
//   xsq float[65536]    : [16777218, 16842754)
// all consumed before k_out overwrites.

typedef _Float16 f16x8 __attribute__((ext_vector_type(8)));
typedef float    f32x4 __attribute__((ext_vector_type(4)));

__device__ __forceinline__ void gl_lds16(const _Float16* g, _Float16* l) {
    __builtin_amdgcn_global_load_lds(
        (const __attribute__((address_space(1))) unsigned int*)g,
        (__attribute__((address_space(3))) unsigned int*)l, 16, 0, 0);
}

// ---- prep: fp32 -> f16 for x and cb; xsq/csq(f32)/csqd(f64); zero counts/nflag
__global__ __launch_bounds__(256) void k_prep(
    const float* __restrict__ x, const float* __restrict__ cb,
    _Float16* __restrict__ xh, _Float16* __restrict__ cbh,
    float* __restrict__ xsq, float* __restrict__ csq, double* __restrict__ csqd,
    unsigned* __restrict__ counts, unsigned* __restrict__ nflag)
{
    const int b = blockIdx.x;
    const int t = threadIdx.x;
    if (b < 8192) {
        const long idx8 = (long)b * 2048 + t * 8;
        float4 v0 = *(const float4*)(x + idx8);
        float4 v1 = *(const float4*)(x + idx8 + 4);
        f16x8 h;
        h[0] = (_Float16)v0.x; h[1] = (_Float16)v0.y; h[2] = (_Float16)v0.z; h[3] = (_Float16)v0.w;
        h[4] = (_Float16)v1.x; h[5] = (_Float16)v1.y; h[6] = (_Float16)v1.z; h[7] = (_Float16)v1.w;
        *(f16x8*)(xh + idx8) = h;
        float sq = v0.x * v0.x + v0.y * v0.y + v0.z * v0.z + v0.w * v0.w
                 + v1.x * v1.x + v1.y * v1.y + v1.z * v1.z + v1.w * v1.w;
        for (int off = 16; off > 0; off >>= 1) sq += __shfl_down(sq, off, 32);
        if ((t & 31) == 0) xsq[b * 8 + (t >> 5)] = sq;
    } else {
        const int b2 = b - 8192;
        const long idx8 = (long)b2 * 2048 + t * 8;
        float4 v0 = *(const float4*)(cb + idx8);
        float4 v1 = *(const float4*)(cb + idx8 + 4);
        f16x8 h;
        h[0] = (_Float16)v0.x; h[1] = (_Float16)v0.y; h[2] = (_Float16)v0.z; h[3] = (_Float16)v0.w;
        h[4] = (_Float16)v1.x; h[5] = (_Float16)v1.y; h[6] = (_Float16)v1.z; h[7] = (_Float16)v1.w;
        *(f16x8*)(cbh + idx8) = h;
        double sqd = (double)v0.x * v0.x + (double)v0.y * v0.y
                   + (double)v0.z * v0.z + (double)v0.w * v0.w
                   + (double)v1.x * v1.x + (double)v1.y * v1.y
                   + (double)v1.z * v1.z + (double)v1.w * v1.w;
        for (int off = 16; off > 0; off >>= 1) sqd += __shfl_down(sqd, off, 32);
        if ((t & 31) == 0) {
            csqd[b2 * 8 + (t >> 5)] = sqd;
            csq[b2 * 8 + (t >> 5)] = (float)sqd;
        }
        if (b2 < 4) counts[b2 * 256 + t] = 0u;
        if (b2 == 0 && t == 0) *nflag = 0u;
    }
}

__device__ __forceinline__ void merge2(float& m1, int& i1, float& m2,
                                       float om1, int oi1, float om2) {
    float hi  = fmaxf(m1, om1);
    float lo2 = fminf(m2, om2);
    bool take = (om1 < m1) || (om1 == m1 && oi1 < i1);
    if (take) { m1 = om1; i1 = oi1; }
    m2 = fminf(hi, lo2);
}

// ---- main: 128-row x 512-code (K-half) MFMA tiles; per-row top-2 per half.
// Register footprint deliberately matches round-2's no-spill config:
// acc[16] f32x4, a[2], b[8], state 8x3. grid = 512 rowTiles x 2 halves.
__global__ __launch_bounds__(256) void k_main(
    const _Float16* __restrict__ xh, const _Float16* __restrict__ cbh,
    const float* __restrict__ csq,
    float* __restrict__ m1h, float* __restrict__ m2h, float* __restrict__ i1f)
{
    __shared__ __attribute__((aligned(16))) _Float16 As[128 * 32]; // 8 KB
    __shared__ __attribute__((aligned(16))) _Float16 Bs[128 * 32]; // 8 KB

    const int tid  = threadIdx.x;
    const int w    = tid >> 6;          // wave -> rows w*32 .. w*32+31
    const int lane = tid & 63;
    const int rlow = lane & 15;
    const int quad = lane >> 4;
    const int rowTile = blockIdx.x >> 1;
    const int half    = blockIdx.x & 1;
    const long n0  = (long)rowTile * 128;
    const int khalf = half * 512;

    float sm1[8], sm2[8];
    int   si1[8];
#pragma unroll
    for (int s = 0; s < 8; s++) { sm1[s] = INFINITY; sm2[s] = INFINITY; si1[s] = 0; }

    for (int kt = 0; kt < 4; ++kt) {
        const int kbase = khalf + kt * 128;
        f32x4 acc[16];
        const f32x4 z = {0.f, 0.f, 0.f, 0.f};
#pragma unroll
        for (int t = 0; t < 16; t++) acc[t] = z;

        for (int d0 = 0; d0 < 256; d0 += 32) {
            __syncthreads();
#pragma unroll
            for (int r = 0; r < 2; ++r) {
                int o = r * 256 + tid;          // 0..511
                gl_lds16(xh  + (n0 + (o >> 2)) * 256 + d0 + (o & 3) * 8, As + o * 8);
                gl_lds16(cbh + (long)(kbase + (o >> 2)) * 256 + d0 + (o & 3) * 8, Bs + o * 8);
            }
            __syncthreads();

            f16x8 a[2], b[8];
#pragma unroll
            for (int i = 0; i < 2; ++i)
                a[i] = *(const f16x8*)&As[(w * 32 + i * 16 + rlow) * 32 + quad * 8];
#pragma unroll
            for (int j = 0; j < 8; ++j)
                b[j] = *(const f16x8*)&Bs[(j * 16 + rlow) * 32 + quad * 8];
#pragma unroll
            for (int i = 0; i < 2; ++i)
#pragma unroll
                for (int j = 0; j < 8; ++j)
                    acc[i * 8 + j] = __builtin_amdgcn_mfma_f32_16x16x32_f16(
                        a[i], b[j], acc[i * 8 + j], 0, 0, 0);
        }

#pragma unroll
        for (int j = 0; j < 8; ++j) {
            const int code = kbase + j * 16 + rlow;
            const float csj = csq[code];
#pragma unroll
            for (int i = 0; i < 2; ++i)
#pragma unroll
                for (int v = 0; v < 4; ++v) {
                    const int s = i * 4 + v;
                    float val = fmaf(-2.f, acc[i * 8 + j][v], csj);
                    bool lt = val < sm1[s];
                    sm2[s] = fminf(fmaxf(val, sm1[s]), sm2[s]);
                    si1[s] = lt ? code : si1[s];
                    sm1[s] = fminf(val, sm1[s]);
                }
        }
    }

#pragma unroll
    for (int s = 0; s < 8; ++s) {
#pragma unroll
        for (int m = 1; m < 16; m <<= 1) {
            float om1 = __shfl_xor(sm1[s], m, 64);
            float om2 = __shfl_xor(sm2[s], m, 64);
            int   oi1 = __shfl_xor(si1[s], m, 64);
            merge2(sm1[s], si1[s], sm2[s], om1, oi1, om2);
        }
    }

    if (rlow == 0) {
        const long hb = (long)half * 65536;
#pragma unroll
        for (int i = 0; i < 2; ++i)
#pragma unroll
            for (int v = 0; v < 4; ++v) {
                const int s = i * 4 + v;
                long n = n0 + w * 32 + i * 16 + quad * 4 + v;
                m1h[hb + n] = sm1[s];
                m2h[hb + n] = sm2[s];
                i1f[hb + n] = (float)si1[s];
            }
    }
}

// ---- merge the two K-halves; flag near-ties; loss partials
__global__ __launch_bounds__(256) void k_merge(
    const float* __restrict__ m1h, const float* __restrict__ m2h,
    const float* __restrict__ i1f, const float* __restrict__ xsq,
    int* __restrict__ min_idx, int* __restrict__ list,
    unsigned* __restrict__ nflag, double* __restrict__ partials)
{
    __shared__ double red[256];
    const int tid = threadIdx.x;
    const int n = blockIdx.x * 256 + tid;

    float m1a = m1h[n], m1b = m1h[65536 + n];
    float m2a = m2h[n], m2b = m2h[65536 + n];
    int   ia  = (int)i1f[n], ib = (int)i1f[65536 + n];

    bool bw = (m1b < m1a) || (m1b == m1a && ib < ia);
    float m1 = bw ? m1b : m1a;
    int   i1 = bw ? ib : ia;
    float m2 = fminf(bw ? m1a : m1b, bw ? m2b : m2a);

    min_idx[n] = i1;
    if (m2 - m1 < TAU) { unsigned p = atomicAdd(nflag, 1u); list[p] = n; }

    red[tid] = (double)xsq[n] + (double)m1;
    __syncthreads();
    for (int off = 128; off > 0; off >>= 1) {
        if (tid < off) red[tid] += red[tid + off];
        __syncthreads();
    }
    if (tid == 0) partials[blockIdx.x] = red[0];
}

// ---- exact fp64 re-rank of flagged rows: 8 rows/block-pass share each cb read.
// dist' = csqd[k] - 2*dot (xsq row-constant -> argmin-invariant). x rows held
// as fp64 in LDS (same-address broadcast reads, conflict-free).
__global__ __launch_bounds__(256) void k_refine(
    const float* __restrict__ x, const float* __restrict__ cb,
    const double* __restrict__ csqd, const unsigned* __restrict__ nflag,
    const int* __restrict__ list, int* __restrict__ min_idx)
{
    __shared__ double xsd[8][256];   // 16 KB
    __shared__ double rbv[4][8];
    __shared__ int    rbi[4][8];
    const int tid = threadIdx.x;
    const int w = tid >> 6, lane = tid & 63;
    const unsigned nf = *nflag;

    for (unsigned base = blockIdx.x * 8u; base < nf; base += gridDim.x * 8u) {
        __syncthreads();
#pragma unroll
        for (int r = 0; r < 2; ++r) {
            int o = r * 256 + tid;          // 0..511
            int row = o >> 6;               // 0..7
            int c4 = (o & 63) * 4;
            unsigned it = base + row; if (it > nf - 1) it = nf - 1;
            int ridx = list[it];
            float4 v = *(const float4*)(x + (long)ridx * D_DIM + c4);
            xsd[row][c4]     = (double)v.x;
            xsd[row][c4 + 1] = (double)v.y;
            xsd[row][c4 + 2] = (double)v.z;
            xsd[row][c4 + 3] = (double)v.w;
        }
        __syncthreads();

        double best[8]; int bidx[8];
#pragma unroll
        for (int r = 0; r < 8; ++r) { best[r] = 1e300; bidx[r] = 0; }

        for (int kk = 0; kk < 4; ++kk) {
            const int k = kk * 256 + tid;
            const float* c = cb + (long)k * D_DIM;
            double s[8];
#pragma unroll
            for (int r = 0; r < 8; ++r) s[r] = 0.0;
            for (int d = 0; d < D_DIM; d += 4) {
                float4 cv = *(const float4*)(c + d);
                double c0 = (double)cv.x, c1 = (double)cv.y;
                double c2 = (double)cv.z, c3 = (double)cv.w;
#pragma unroll
                for (int r = 0; r < 8; ++r) {
                    s[r] = fma(xsd[r][d],     c0, s[r]);
                    s[r] = fma(xsd[r][d + 1], c1, s[r]);
                    s[r] = fma(xsd[r][d + 2], c2, s[r]);
                    s[r] = fma(xsd[r][d + 3], c3, s[r]);
                }
            }
            const double ck = csqd[k];
#pragma unroll
            for (int r = 0; r < 8; ++r) {
                double dist = fma(-2.0, s[r], ck);
                if (dist < best[r] || (dist == best[r] && k < bidx[r])) {
                    best[r] = dist; bidx[r] = k;
                }
            }
        }

#pragma unroll
        for (int r = 0; r < 8; ++r) {
            for (int off = 32; off > 0; off >>= 1) {
                double od = __shfl_down(best[r], off, 64);
                int    oi = __shfl_down(bidx[r], off, 64);
                if (od < best[r] || (od == best[r] && oi < bidx[r])) {
                    best[r] = od; bidx[r] = oi;
                }
            }
        }
        if (lane == 0) {
#pragma unroll
            for (int r = 0; r < 8; ++r) { rbv[w][r] = best[r]; rbi[w][r] = bidx[r]; }
        }
        __syncthreads();
        if (tid < 8 && base + tid < nf) {
            double bb = rbv[0][tid]; int bi_ = rbi[0][tid];
#pragma unroll
            for (int wv = 1; wv < 4; ++wv) {
                if (rbv[wv][tid] < bb || (rbv[wv][tid] == bb && rbi[wv][tid] < bi_)) {
                    bb = rbv[wv][tid]; bi_ = rbi[wv][tid];
                }
            }
            min_idx[list[base + tid]] = bi_;
        }
        __syncthreads();
    }
}

// ---- gather quantized rows, histogram, index output
__global__ __launch_bounds__(256) void k_out(
    const float* __restrict__ cb, const int* __restrict__ min_idx,
    float* __restrict__ out, unsigned* __restrict__ counts)
{
    const int tid  = threadIdx.x;
    const int wave = tid >> 6;
    const int lane = tid & 63;
    const long n = (long)blockIdx.x * 4 + wave;
    const int idx = min_idx[n];

    float4 q = *(const float4*)(cb + (long)idx * D_DIM + lane * 4);
    *(float4*)(out + n * D_DIM + lane * 4) = q;

    if (lane == 0) {
        atomicAdd(&counts[idx], 1u);
        out[16777218L + n] = (float)idx;
    }
}

__global__ void k_final(const double* __restrict__ partials,
                        const unsigned* __restrict__ counts, float* __restrict__ out)
{
    __shared__ double red[256];
    const int tid = threadIdx.x;

    red[tid] = partials[tid];
    __syncthreads();
    for (int off = 128; off > 0; off >>= 1) { if (tid < off) red[tid] += red[tid + off]; __syncthreads(); }
    double loss = red[0] / (double)((long)N_ROWS * D_DIM);
    __syncthreads();

    double h = 0.0;
    for (int k = tid; k < K_CODES; k += 256) {
        double p = (double)counts[k] / (double)N_ROWS;
        h += p * log(p + 1e-10);
    }
    red[tid] = h;
    __syncthreads();
    for (int off = 128; off > 0; off >>= 1) { if (tid < off) red[tid] += red[tid + off]; __syncthreads(); }

    if (tid == 0) {
        out[16777216] = (float)loss;
        out[16777217] = (float)exp(-red[0]);
    }
}

extern "C" void kernel_launch(void* const* d_in, const int* in_sizes, int n_in,
                              void* d_out, int out_size, void* d_ws, size_t ws_size,
                              hipStream_t stream)
{
    const float* x  = (const float*)d_in[0];
    const float* cb = (const float*)d_in[1];
    float* out = (float*)d_out;
    char*  ws  = (char*)d_ws;

    unsigned*  nflag    = (unsigned*)(ws + WS_NFLAG);
    float*     csq      = (float*)(ws + WS_CSQ);
    unsigned*  counts   = (unsigned*)(ws + WS_COUNTS);
    int*       min_idx  = (int*)(ws + WS_MINIDX);
    int*       list     = (int*)(ws + WS_LIST);
    double*    partials = (double*)(ws + WS_PART);
    double*    csqd     = (double*)(ws + WS_CSQD);
    _Float16*  cbh      = (_Float16*)(ws + WS_CBH);
    _Float16*  xh       = (_Float16*)d_out;          // floats [0, 8388608)
    float*     m1h      = out + 8388608L;
    float*     m2h      = out + 8519680L;
    float*     i1f      = out + 8650752L;
    float*     xsq      = out + 16777218L;

    hipLaunchKernelGGL(k_prep,   dim3(8192 + 128), dim3(256), 0, stream,
                       x, cb, xh, cbh, xsq, csq, csqd, counts, nflag);
    hipLaunchKernelGGL(k_main,   dim3(1024), dim3(256), 0, stream,
                       xh, cbh, csq, m1h, m2h, i1f);
    hipLaunchKernelGGL(k_merge,  dim3(256), dim3(256), 0, stream,
                       m1h, m2h, i1f, xsq, min_idx, list, nflag, partials);
    hipLaunchKernelGGL(k_refine, dim3(512), dim3(256), 0, stream,
                       x, cb, csqd, nflag, list, min_idx);
    hipLaunchKernelGGL(k_out,    dim3(N_ROWS / 4), dim3(256), 0, stream,
                       cb, min_idx, out, counts);
    hipLaunchKernelGGL(k_final,  dim3(1), dim3(256), 0, stream, partials, counts, out);
}